// Round 1
// baseline (185.264 us; speedup 1.0000x reference)
//
#include <hip/hip_runtime.h>
#include <math.h>

#define BLOCK 256
#define FPC   256            // frames per chunk (== BLOCK, one frame per thread)
#define NBLOCKS 2048

__global__ __launch_bounds__(BLOCK) void rmse_partial_kernel(
    const float* __restrict__ rot_kf, const float* __restrict__ pose_kf,
    const float* __restrict__ rot_gt, const float* __restrict__ pose_gt,
    float* __restrict__ partial, int N)
{
    // 36 KB staging buffer (reused for rot_kf then rot_gt) -> 4 blocks/CU
    __shared__ float lds[FPC * 9];
    __shared__ float redbuf[BLOCK / 64];

    const int tid = threadIdx.x;
    const long long totalRot = (long long)N * 9;
    const int nChunks = (N + FPC - 1) / FPC;

    float sum = 0.0f;
    float a[9], b[9];

    for (int c = blockIdx.x; c < nChunks; c += gridDim.x) {
        const long long base = (long long)c * (FPC * 9);   // float index into rot arrays
        const int frame = c * FPC + tid;

        // ---- stage rot_kf chunk (coalesced float4) ----
        __syncthreads();   // protect LDS reads of previous iteration
        #pragma unroll
        for (int j = 0; j < 9; ++j) {
            const long long f4 = base / 4 + (long long)j * BLOCK + tid;  // float4 index
            const long long e  = f4 * 4;
            float4 v;
            if (e + 3 < totalRot) {
                v = reinterpret_cast<const float4*>(rot_kf)[f4];
            } else {
                v.x = (e + 0 < totalRot) ? rot_kf[e + 0] : 0.0f;
                v.y = (e + 1 < totalRot) ? rot_kf[e + 1] : 0.0f;
                v.z = (e + 2 < totalRot) ? rot_kf[e + 2] : 0.0f;
                v.w = 0.0f;
            }
            reinterpret_cast<float4*>(lds)[j * BLOCK + tid] = v;
        }
        __syncthreads();
        #pragma unroll
        for (int j = 0; j < 9; ++j) a[j] = lds[tid * 9 + j];
        __syncthreads();   // done reading A, safe to restage

        // ---- stage rot_gt chunk ----
        #pragma unroll
        for (int j = 0; j < 9; ++j) {
            const long long f4 = base / 4 + (long long)j * BLOCK + tid;
            const long long e  = f4 * 4;
            float4 v;
            if (e + 3 < totalRot) {
                v = reinterpret_cast<const float4*>(rot_gt)[f4];
            } else {
                v.x = (e + 0 < totalRot) ? rot_gt[e + 0] : 0.0f;
                v.y = (e + 1 < totalRot) ? rot_gt[e + 1] : 0.0f;
                v.z = (e + 2 < totalRot) ? rot_gt[e + 2] : 0.0f;
                v.w = 0.0f;
            }
            reinterpret_cast<float4*>(lds)[j * BLOCK + tid] = v;
        }
        __syncthreads();
        #pragma unroll
        for (int j = 0; j < 9; ++j) b[j] = lds[tid * 9 + j];
        // (top-of-loop barrier protects these reads before next restage)

        if (frame < N) {
            const long long p = (long long)frame * 3;
            const float d0 = pose_gt[p + 0] - pose_kf[p + 0];
            const float d1 = pose_gt[p + 1] - pose_kf[p + 1];
            const float d2 = pose_gt[p + 2] - pose_kf[p + 2];

            float s = 0.0f;
            #pragma unroll
            for (int i = 0; i < 3; ++i) {
                #pragma unroll
                for (int k = 0; k < 3; ++k) {
                    // R_rel[i][k] = sum_j A[j][i] * B[j][k]   (A = rot_kf, B = rot_gt)
                    float r = a[i] * b[k] + a[3 + i] * b[3 + k] + a[6 + i] * b[6 + k];
                    r -= (i == k) ? 1.0f : 0.0f;
                    s += r * r;
                }
                // t_rel[i] = sum_j A[j][i] * d[j]
                const float t = a[i] * d0 + a[3 + i] * d1 + a[6 + i] * d2;
                s += t * t;
            }
            sum += s;
        }
    }

    // ---- block reduction ----
    const int lane = tid & 63;
    const int wave = tid >> 6;
    #pragma unroll
    for (int off = 32; off > 0; off >>= 1) sum += __shfl_down(sum, off);
    if (lane == 0) redbuf[wave] = sum;
    __syncthreads();
    if (tid == 0) {
        float s = 0.0f;
        #pragma unroll
        for (int w = 0; w < BLOCK / 64; ++w) s += redbuf[w];
        partial[blockIdx.x] = s;
    }
}

__global__ __launch_bounds__(BLOCK) void rmse_finalize_kernel(
    const float* __restrict__ partial, int nPartial, float* __restrict__ out, int N)
{
    __shared__ float redbuf[BLOCK / 64];
    float sum = 0.0f;
    for (int i = threadIdx.x; i < nPartial; i += BLOCK) sum += partial[i];
    #pragma unroll
    for (int off = 32; off > 0; off >>= 1) sum += __shfl_down(sum, off);
    const int lane = threadIdx.x & 63;
    const int wave = threadIdx.x >> 6;
    if (lane == 0) redbuf[wave] = sum;
    __syncthreads();
    if (threadIdx.x == 0) {
        float s = 0.0f;
        #pragma unroll
        for (int w = 0; w < BLOCK / 64; ++w) s += redbuf[w];
        out[0] = sqrtf(s / (float)N) + 1e-8f;
    }
}

extern "C" void kernel_launch(void* const* d_in, const int* in_sizes, int n_in,
                              void* d_out, int out_size, void* d_ws, size_t ws_size,
                              hipStream_t stream) {
    const float* rot_kf  = (const float*)d_in[0];
    const float* pose_kf = (const float*)d_in[1];
    const float* rot_gt  = (const float*)d_in[2];
    const float* pose_gt = (const float*)d_in[3];
    float* out = (float*)d_out;
    float* partial = (float*)d_ws;

    const int N = in_sizes[1] / 3;   // pose_kf is [N,3]
    const int nChunks = (N + FPC - 1) / FPC;

    int grid = NBLOCKS;
    if (grid > nChunks) grid = nChunks;
    const int wsCap = (int)(ws_size / sizeof(float));
    if (grid > wsCap) grid = wsCap;
    if (grid < 1) grid = 1;

    rmse_partial_kernel<<<grid, BLOCK, 0, stream>>>(rot_kf, pose_kf, rot_gt, pose_gt, partial, N);
    rmse_finalize_kernel<<<1, BLOCK, 0, stream>>>(partial, grid, out, N);
}

// Round 2
// 72.619 us; speedup vs baseline: 2.5512x; 2.5512x over previous
//
#include <hip/hip_runtime.h>
#include <math.h>

#define BLOCK 256
#define FPT   4                 // frames per thread
#define FPC   (BLOCK * FPT)     // 1024 frames per chunk
#define NBLOCKS 2048

// Per chunk, per rot array: FPC*9 floats = 2304 float4 = 9 float4 per thread.
#define ROT_F4_PER_CHUNK (FPC * 9 / 4)   // 2304

__global__ __launch_bounds__(BLOCK) void rmse_partial_kernel(
    const float* __restrict__ rot_kf, const float* __restrict__ pose_kf,
    const float* __restrict__ rot_gt, const float* __restrict__ pose_gt,
    float* __restrict__ partial, int N)
{
    __shared__ float lds[FPC * 9];          // 36864 B, reused for A then B
    __shared__ float redbuf[BLOCK / 64];

    const int tid = threadIdx.x;
    const long long totalRot = (long long)N * 9;
    const int nChunks = (N + FPC - 1) / FPC;

    float sum = 0.0f;
    float a[FPT][9];

    for (int c = blockIdx.x; c < nChunks; c += gridDim.x) {
        const long long base4 = (long long)c * ROT_F4_PER_CHUNK;  // float4 index

        // ---- stage rot_kf chunk: 2304 contiguous float4, 9 per thread ----
        __syncthreads();   // protect LDS reads of previous iteration
        #pragma unroll
        for (int j = 0; j < 9; ++j) {
            const long long f4 = base4 + (long long)j * BLOCK + tid;
            const long long e  = f4 * 4;
            float4 v;
            if (e + 3 < totalRot) {
                v = reinterpret_cast<const float4*>(rot_kf)[f4];
            } else {
                v.x = (e + 0 < totalRot) ? rot_kf[e + 0] : 0.0f;
                v.y = (e + 1 < totalRot) ? rot_kf[e + 1] : 0.0f;
                v.z = (e + 2 < totalRot) ? rot_kf[e + 2] : 0.0f;
                v.w = 0.0f;
            }
            reinterpret_cast<float4*>(lds)[j * BLOCK + tid] = v;
        }
        __syncthreads();
        #pragma unroll
        for (int s = 0; s < FPT; ++s) {
            #pragma unroll
            for (int j = 0; j < 9; ++j) a[s][j] = lds[(s * BLOCK + tid) * 9 + j];
        }
        __syncthreads();   // done reading A, safe to restage

        // ---- stage rot_gt chunk ----
        #pragma unroll
        for (int j = 0; j < 9; ++j) {
            const long long f4 = base4 + (long long)j * BLOCK + tid;
            const long long e  = f4 * 4;
            float4 v;
            if (e + 3 < totalRot) {
                v = reinterpret_cast<const float4*>(rot_gt)[f4];
            } else {
                v.x = (e + 0 < totalRot) ? rot_gt[e + 0] : 0.0f;
                v.y = (e + 1 < totalRot) ? rot_gt[e + 1] : 0.0f;
                v.z = (e + 2 < totalRot) ? rot_gt[e + 2] : 0.0f;
                v.w = 0.0f;
            }
            reinterpret_cast<float4*>(lds)[j * BLOCK + tid] = v;
        }
        __syncthreads();

        #pragma unroll
        for (int s = 0; s < FPT; ++s) {
            const int frame = c * FPC + s * BLOCK + tid;
            if (frame < N) {
                float b[9];
                #pragma unroll
                for (int j = 0; j < 9; ++j) b[j] = lds[(s * BLOCK + tid) * 9 + j];

                const long long p = (long long)frame * 3;
                const float d0 = pose_gt[p + 0] - pose_kf[p + 0];
                const float d1 = pose_gt[p + 1] - pose_kf[p + 1];
                const float d2 = pose_gt[p + 2] - pose_kf[p + 2];

                float s_err = 0.0f;
                #pragma unroll
                for (int i = 0; i < 3; ++i) {
                    #pragma unroll
                    for (int k = 0; k < 3; ++k) {
                        // R_rel[i][k] = sum_j A[j][i] * B[j][k]
                        float r = a[s][i] * b[k] + a[s][3 + i] * b[3 + k] + a[s][6 + i] * b[6 + k];
                        r -= (i == k) ? 1.0f : 0.0f;
                        s_err += r * r;
                    }
                    // t_rel[i] = sum_j A[j][i] * d[j]
                    const float t = a[s][i] * d0 + a[s][3 + i] * d1 + a[s][6 + i] * d2;
                    s_err += t * t;
                }
                sum += s_err;
            }
        }
        // top-of-loop barrier protects B reads before next restage
    }

    // ---- block reduction ----
    const int lane = tid & 63;
    const int wave = tid >> 6;
    #pragma unroll
    for (int off = 32; off > 0; off >>= 1) sum += __shfl_down(sum, off);
    if (lane == 0) redbuf[wave] = sum;
    __syncthreads();
    if (tid == 0) {
        float s = 0.0f;
        #pragma unroll
        for (int w = 0; w < BLOCK / 64; ++w) s += redbuf[w];
        partial[blockIdx.x] = s;
    }
}

__global__ __launch_bounds__(BLOCK) void rmse_finalize_kernel(
    const float* __restrict__ partial, int nPartial, float* __restrict__ out, int N)
{
    __shared__ float redbuf[BLOCK / 64];
    float sum = 0.0f;
    for (int i = threadIdx.x; i < nPartial; i += BLOCK) sum += partial[i];
    #pragma unroll
    for (int off = 32; off > 0; off >>= 1) sum += __shfl_down(sum, off);
    const int lane = threadIdx.x & 63;
    const int wave = threadIdx.x >> 6;
    if (lane == 0) redbuf[wave] = sum;
    __syncthreads();
    if (threadIdx.x == 0) {
        float s = 0.0f;
        #pragma unroll
        for (int w = 0; w < BLOCK / 64; ++w) s += redbuf[w];
        out[0] = sqrtf(s / (float)N) + 1e-8f;
    }
}

extern "C" void kernel_launch(void* const* d_in, const int* in_sizes, int n_in,
                              void* d_out, int out_size, void* d_ws, size_t ws_size,
                              hipStream_t stream) {
    const float* rot_kf  = (const float*)d_in[0];
    const float* pose_kf = (const float*)d_in[1];
    const float* rot_gt  = (const float*)d_in[2];
    const float* pose_gt = (const float*)d_in[3];
    float* out = (float*)d_out;
    float* partial = (float*)d_ws;

    const int N = in_sizes[1] / 3;   // pose_kf is [N,3]
    const int nChunks = (N + FPC - 1) / FPC;

    int grid = NBLOCKS;
    if (grid > nChunks) grid = nChunks;
    const int wsCap = (int)(ws_size / sizeof(float));
    if (grid > wsCap) grid = wsCap;
    if (grid < 1) grid = 1;

    rmse_partial_kernel<<<grid, BLOCK, 0, stream>>>(rot_kf, pose_kf, rot_gt, pose_gt, partial, N);
    rmse_finalize_kernel<<<1, BLOCK, 0, stream>>>(partial, grid, out, N);
}